// Round 4
// baseline (292.543 us; speedup 1.0000x reference)
//
#include <hip/hip_runtime.h>
#include <stdint.h>

#define INF 8192        // IN features
#define OUTF 8192       // OUT features
#define TOK 16          // tokens (2*8)
#define KSPLIT 8
#define KR (INF / KSPLIT)          // 1024 K per block
#define NI (KR / 32)               // 32 MFMA iters per wave
#define ROWS_PER_BLOCK 64          // 4 waves * 16 rows
#define LDS_STRIDE (KR + 8)        // bf16 elems, padded (1032)
#define NRG (OUTF / ROWS_PER_BLOCK)   // 128 row groups

typedef __attribute__((ext_vector_type(8))) short short8;
typedef __attribute__((ext_vector_type(4))) short short4v;
typedef __attribute__((ext_vector_type(4))) float float4v;
typedef __attribute__((ext_vector_type(4))) int int4v;
typedef __attribute__((ext_vector_type(4))) uint32_t uint4v;

__device__ __forceinline__ short f2bf(float f) {
    uint32_t u = __builtin_bit_cast(uint32_t, f);
    u += 0x7fffu + ((u >> 16) & 1u);   // round-to-nearest-even
    return (short)(u >> 16);
}

// pack two floats to 2 bf16 (round-half-up) in one u32: a->low, b->high
__device__ __forceinline__ uint32_t pkbf(float a, float b) {
    uint32_t ua = __builtin_bit_cast(uint32_t, a) + 0x8000u;
    uint32_t ub = __builtin_bit_cast(uint32_t, b) + 0x8000u;
    return (ua >> 16) | (ub & 0xffff0000u);
}

// Stage x[0..15][k0..k0+KR) into LDS as bf16 (padded stride).
__device__ __forceinline__ void stage_x(const float* __restrict__ x, short* xs,
                                        int k0, int tid) {
    #pragma unroll
    for (int it = 0; it < (TOK * KR / 4) / 256; ++it) {   // 16 iters
        int idx = tid + it * 256;
        int t  = idx >> 8;        // KR/4 = 256 float4 per token row
        int kq = idx & 255;
        float4v xv = *reinterpret_cast<const float4v*>(x + (size_t)t * INF + k0 + kq * 4);
        short4v h;
        h[0] = f2bf(xv[0]); h[1] = f2bf(xv[1]); h[2] = f2bf(xv[2]); h[3] = f2bf(xv[3]);
        *reinterpret_cast<short4v*>(xs + t * LDS_STRIDE + kq * 4) = h;
    }
}

// ---------------- fused single-dispatch kernel ----------------
__global__ __launch_bounds__(256, 4) void gemm_q8_fused(
    const float* __restrict__ x, const int* __restrict__ qw,
    const float* __restrict__ scales, const float* __restrict__ bias,
    float* __restrict__ pbuf, unsigned int* __restrict__ cnt,
    float* __restrict__ out)
{
    __shared__ short xs[TOK * LDS_STRIDE];
    __shared__ int is_last;
    int bid = blockIdx.x;
    int rg = bid >> 3;                 // 0..127 row groups
    int ks = bid & 7;                  // 0..7 k splits
    int k0 = ks * KR;
    int tid = threadIdx.x;
    int wave = tid >> 6;
    int lane = tid & 63;
    int col  = lane & 15;
    int kg   = lane >> 4;
    int r0 = rg * ROWS_PER_BLOCK + wave * 16;
    int r  = r0 + col;

    const int*   qrow = qw + (size_t)r * INF + k0 + kg * 8;
    const float* srow = scales + (size_t)r * (INF / 32) + (k0 >> 5);

    // k-phase rotation: decorrelate HBM channel targeting across blocks/waves
    int phase = ((rg * 5) + wave * 11) & (NI - 1);

    // issue first q loads BEFORE x staging so the HBM q stream starts now
    int j0 = phase;
    int j1 = (phase + 1) & (NI - 1);
    int4v A0 = *reinterpret_cast<const int4v*>(qrow + j0 * 32);
    int4v B0 = *reinterpret_cast<const int4v*>(qrow + j0 * 32 + 4);
    int4v A1 = *reinterpret_cast<const int4v*>(qrow + j1 * 32);
    int4v B1 = *reinterpret_cast<const int4v*>(qrow + j1 * 32 + 4);
    float s0 = srow[j0], s1 = srow[j1];

    stage_x(x, xs, k0, tid);
    __syncthreads();

    const short* aptr = xs + col * LDS_STRIDE + kg * 8;
    float4v acc = {0.f, 0.f, 0.f, 0.f};
    int ji = phase;

    #pragma unroll 4
    for (int i = 0; i < NI; ++i) {
        int ipl = (i + 2 < NI) ? (i + 2) : (NI - 1);
        int j2 = (ipl + phase) & (NI - 1);
        int4v A2 = *reinterpret_cast<const int4v*>(qrow + j2 * 32);
        int4v B2 = *reinterpret_cast<const int4v*>(qrow + j2 * 32 + 4);
        float s2 = srow[j2];

        float m = -127.0f * s0;
        float f0 = fmaf((float)A0[0], s0, m);
        float f1 = fmaf((float)A0[1], s0, m);
        float f2 = fmaf((float)A0[2], s0, m);
        float f3 = fmaf((float)A0[3], s0, m);
        float f4 = fmaf((float)B0[0], s0, m);
        float f5 = fmaf((float)B0[1], s0, m);
        float f6 = fmaf((float)B0[2], s0, m);
        float f7 = fmaf((float)B0[3], s0, m);

        uint4v pk;
        pk[0] = pkbf(f0, f1);
        pk[1] = pkbf(f2, f3);
        pk[2] = pkbf(f4, f5);
        pk[3] = pkbf(f6, f7);
        short8 bfrag = __builtin_bit_cast(short8, pk);

        short8 afrag = *reinterpret_cast<const short8*>(aptr + ji * 32);

        acc = __builtin_amdgcn_mfma_f32_16x16x32_bf16(afrag, bfrag, acc, 0, 0, 0);

        A0 = A1; B0 = B1; s0 = s1;
        A1 = A2; B1 = B2; s1 = s2;
        ji = (ji + 1) & (NI - 1);
    }

    // publish partial: pbuf[ks][t][OUTF]
    float* pb = pbuf + (size_t)ks * TOK * OUTF;
    #pragma unroll
    for (int i = 0; i < 4; ++i) {
        int t = kg * 4 + i;
        pb[(size_t)t * OUTF + r0 + col] = acc[i];
    }

    // last-arrival reduction (canonical threadfence-reduction pattern)
    __threadfence();
    __syncthreads();
    if (tid == 0) {
        unsigned int old = atomicAdd(&cnt[rg], 1u);
        is_last = (old == KSPLIT - 1);
    }
    __syncthreads();
    if (is_last) {
        __threadfence();   // acquire: see other blocks' partial stores
        int rr = rg * ROWS_PER_BLOCK + (tid & 63);
        int tb = tid >> 6;             // 0..3
        for (int t = tb; t < TOK; t += 4) {
            float a = bias[rr];
            #pragma unroll
            for (int s = 0; s < KSPLIT; ++s)
                a += pbuf[(size_t)(s * TOK + t) * OUTF + rr];
            out[(size_t)t * OUTF + rr] = a;
        }
    }
}

// ---------------- fallback two-kernel path ----------------
__device__ __forceinline__ float4v kloop(const short* xs,
                                         const int* __restrict__ qrow,
                                         const float* __restrict__ srow,
                                         int lane, float4v acc) {
    int col = lane & 15;
    int kg  = lane >> 4;
    const short* aptr = xs + col * LDS_STRIDE + kg * 8;

    int4v A0 = *reinterpret_cast<const int4v*>(qrow);
    int4v B0 = *reinterpret_cast<const int4v*>(qrow + 4);
    int4v A1 = *reinterpret_cast<const int4v*>(qrow + 32);
    int4v B1 = *reinterpret_cast<const int4v*>(qrow + 36);
    float s0 = srow[0], s1 = srow[1];

    #pragma unroll 4
    for (int i = 0; i < NI; ++i) {
        int ip = (i + 2 < NI) ? (i + 2) : (NI - 1);
        int4v A2 = *reinterpret_cast<const int4v*>(qrow + ip * 32);
        int4v B2 = *reinterpret_cast<const int4v*>(qrow + ip * 32 + 4);
        float s2 = srow[ip];

        float m = -127.0f * s0;
        float f0 = fmaf((float)A0[0], s0, m);
        float f1 = fmaf((float)A0[1], s0, m);
        float f2 = fmaf((float)A0[2], s0, m);
        float f3 = fmaf((float)A0[3], s0, m);
        float f4 = fmaf((float)B0[0], s0, m);
        float f5 = fmaf((float)B0[1], s0, m);
        float f6 = fmaf((float)B0[2], s0, m);
        float f7 = fmaf((float)B0[3], s0, m);

        uint4v pk;
        pk[0] = pkbf(f0, f1);
        pk[1] = pkbf(f2, f3);
        pk[2] = pkbf(f4, f5);
        pk[3] = pkbf(f6, f7);
        short8 bfrag = __builtin_bit_cast(short8, pk);

        short8 afrag = *reinterpret_cast<const short8*>(aptr + i * 32);

        acc = __builtin_amdgcn_mfma_f32_16x16x32_bf16(afrag, bfrag, acc, 0, 0, 0);

        A0 = A1; B0 = B1; s0 = s1;
        A1 = A2; B1 = B2; s1 = s2;
    }
    return acc;
}

__global__ __launch_bounds__(256, 4) void gemm_q8_part(
    const float* __restrict__ x, const int* __restrict__ qw,
    const float* __restrict__ scales, float* __restrict__ pbuf)
{
    __shared__ short xs[TOK * LDS_STRIDE];
    int rg = blockIdx.x >> 3;
    int ks = blockIdx.x & 7;
    int k0 = ks * KR;
    int tid = threadIdx.x;

    stage_x(x, xs, k0, tid);
    __syncthreads();

    int wave = tid >> 6;
    int lane = tid & 63;
    int col  = lane & 15;
    int kg   = lane >> 4;
    int r0 = rg * ROWS_PER_BLOCK + wave * 16;
    int r  = r0 + col;

    const int*   qrow = qw + (size_t)r * INF + k0 + kg * 8;
    const float* srow = scales + (size_t)r * (INF / 32) + (k0 >> 5);

    float4v acc = {0.f, 0.f, 0.f, 0.f};
    acc = kloop(xs, qrow, srow, lane, acc);

    float* pb = pbuf + (size_t)ks * TOK * OUTF;
    #pragma unroll
    for (int i = 0; i < 4; ++i) {
        int t = kg * 4 + i;
        pb[(size_t)t * OUTF + r0 + col] = acc[i];
    }
}

__global__ __launch_bounds__(256) void reduce_bias_k(
    const float* __restrict__ pbuf, const float* __restrict__ bias,
    float* __restrict__ out)
{
    int gid = blockIdx.x * 256 + threadIdx.x;
    int f = gid * 4;
    int t = f >> 13;
    int r = f & (OUTF - 1);
    float4v a = *reinterpret_cast<const float4v*>(bias + r);
    #pragma unroll
    for (int s = 0; s < KSPLIT; ++s) {
        float4v p = *reinterpret_cast<const float4v*>(pbuf + (size_t)(s * TOK + t) * OUTF + r);
        a += p;
    }
    *reinterpret_cast<float4v*>(out + f) = a;
}

__global__ __launch_bounds__(256, 4) void gemm_q8_direct(
    const float* __restrict__ x, const int* __restrict__ qw,
    const float* __restrict__ scales, const float* __restrict__ bias,
    float* __restrict__ out)
{
    __shared__ short xs[TOK * LDS_STRIDE];
    int rg = blockIdx.x;
    int tid = threadIdx.x;
    int wave = tid >> 6;
    int lane = tid & 63;
    int col  = lane & 15;
    int kg   = lane >> 4;
    int r0 = rg * ROWS_PER_BLOCK + wave * 16;
    int r  = r0 + col;

    float4v acc = {0.f, 0.f, 0.f, 0.f};
    for (int ks = 0; ks < KSPLIT; ++ks) {
        int k0 = ks * KR;
        __syncthreads();
        stage_x(x, xs, k0, tid);
        __syncthreads();
        const int*   qrow = qw + (size_t)r * INF + k0 + kg * 8;
        const float* srow = scales + (size_t)r * (INF / 32) + (k0 >> 5);
        acc = kloop(xs, qrow, srow, lane, acc);
    }
    #pragma unroll
    for (int i = 0; i < 4; ++i) {
        int t = kg * 4 + i;
        out[(size_t)t * OUTF + r0 + col] = acc[i] + bias[r0 + col];
    }
}

extern "C" void kernel_launch(void* const* d_in, const int* in_sizes, int n_in,
                              void* d_out, int out_size, void* d_ws, size_t ws_size,
                              hipStream_t stream) {
    const float* x      = (const float*)d_in[0];
    const int*   qw     = (const int*)d_in[1];
    const float* scales = (const float*)d_in[2];
    const float* bias   = (const float*)d_in[3];
    float* out = (float*)d_out;

    size_t pbytes = (size_t)KSPLIT * TOK * OUTF * sizeof(float);   // 4 MB
    size_t cbytes = NRG * sizeof(unsigned int);                    // 512 B

    if (ws_size >= pbytes + cbytes) {
        float* pbuf = (float*)d_ws;
        unsigned int* cnt = (unsigned int*)((char*)d_ws + pbytes);
        hipMemsetAsync(cnt, 0, cbytes, stream);
        gemm_q8_fused<<<NRG * KSPLIT, 256, 0, stream>>>(x, qw, scales, bias, pbuf, cnt, out);
    } else if (ws_size >= pbytes) {
        float* pbuf = (float*)d_ws;
        gemm_q8_part<<<NRG * KSPLIT, 256, 0, stream>>>(x, qw, scales, pbuf);
        reduce_bias_k<<<(TOK * OUTF / 4) / 256, 256, 0, stream>>>(pbuf, bias, out);
    } else {
        gemm_q8_direct<<<NRG, 256, 0, stream>>>(x, qw, scales, bias, out);
    }
}

// Round 5
// 67.790 us; speedup vs baseline: 4.3154x; 4.3154x over previous
//
#include <hip/hip_runtime.h>
#include <stdint.h>

#define INF 8192        // IN features
#define OUTF 8192       // OUT features
#define TOK 16          // tokens (2*8)
#define KSPLIT 8
#define KR (INF / KSPLIT)          // 1024 K per block
#define NI (KR / 32)               // 32 MFMA iters per wave
#define ROWS_PER_BLOCK 64          // 4 waves * 16 rows
#define LDS_STRIDE (KR + 8)        // bf16 elems, padded (1032)
#define NRG (OUTF / ROWS_PER_BLOCK)   // 128 row groups

typedef __attribute__((ext_vector_type(8))) short short8;
typedef __attribute__((ext_vector_type(4))) short short4v;
typedef __attribute__((ext_vector_type(4))) float float4v;
typedef __attribute__((ext_vector_type(4))) int int4v;
typedef __attribute__((ext_vector_type(4))) uint32_t uint4v;

__device__ __forceinline__ short f2bf(float f) {
    uint32_t u = __builtin_bit_cast(uint32_t, f);
    u += 0x7fffu + ((u >> 16) & 1u);   // round-to-nearest-even
    return (short)(u >> 16);
}

// pack two floats to 2 bf16 (round-half-up) in one u32: a->low, b->high
__device__ __forceinline__ uint32_t pkbf(float a, float b) {
    uint32_t ua = __builtin_bit_cast(uint32_t, a) + 0x8000u;
    uint32_t ub = __builtin_bit_cast(uint32_t, b) + 0x8000u;
    return (ua >> 16) | (ub & 0xffff0000u);
}

// Stage x[0..15][k0..k0+KR) into LDS as bf16 (padded stride).
__device__ __forceinline__ void stage_x(const float* __restrict__ x, short* xs,
                                        int k0, int tid) {
    #pragma unroll
    for (int it = 0; it < (TOK * KR / 4) / 256; ++it) {   // 16 iters
        int idx = tid + it * 256;
        int t  = idx >> 8;        // KR/4 = 256 float4 per token row
        int kq = idx & 255;
        float4v xv = *reinterpret_cast<const float4v*>(x + (size_t)t * INF + k0 + kq * 4);
        short4v h;
        h[0] = f2bf(xv[0]); h[1] = f2bf(xv[1]); h[2] = f2bf(xv[2]); h[3] = f2bf(xv[3]);
        *reinterpret_cast<short4v*>(xs + t * LDS_STRIDE + kq * 4) = h;
    }
}

// Dequant one 8-code group to a bf16 MFMA B-fragment.
__device__ __forceinline__ short8 dequant8(int4v A, int4v B, float s) {
    float m = -127.0f * s;
    float f0 = fmaf((float)A[0], s, m);
    float f1 = fmaf((float)A[1], s, m);
    float f2 = fmaf((float)A[2], s, m);
    float f3 = fmaf((float)A[3], s, m);
    float f4 = fmaf((float)B[0], s, m);
    float f5 = fmaf((float)B[1], s, m);
    float f6 = fmaf((float)B[2], s, m);
    float f7 = fmaf((float)B[3], s, m);
    uint4v pk;
    pk[0] = pkbf(f0, f1);
    pk[1] = pkbf(f2, f3);
    pk[2] = pkbf(f4, f5);
    pk[3] = pkbf(f6, f7);
    return __builtin_bit_cast(short8, pk);
}

// ---------------- main split-K kernel (two-dispatch path) ----------------
__global__ __launch_bounds__(256, 4) void gemm_q8_part(
    const float* __restrict__ x, const int* __restrict__ qw,
    const float* __restrict__ scales, float* __restrict__ pbuf)
{
    __shared__ short xs[TOK * LDS_STRIDE];
    int rg = blockIdx.x >> 3;          // 0..127 row groups
    int ks = blockIdx.x & 7;           // 0..7 k splits
    int k0 = ks * KR;
    int tid = threadIdx.x;
    int wave = tid >> 6;
    int lane = tid & 63;
    int col  = lane & 15;
    int kg   = lane >> 4;
    int r0 = rg * ROWS_PER_BLOCK + wave * 16;
    int r  = r0 + col;

    const int*   qrow = qw + (size_t)r * INF + k0 + kg * 8;
    const float* srow = scales + (size_t)r * (INF / 32) + (k0 >> 5);

    // Depth-3 prefetch issued BEFORE x staging: q stream starts at cycle ~0,
    // q loads are oldest in the vmcnt queue so they retire under staging.
    int4v A0 = *reinterpret_cast<const int4v*>(qrow);
    int4v B0 = *reinterpret_cast<const int4v*>(qrow + 4);
    int4v A1 = *reinterpret_cast<const int4v*>(qrow + 32);
    int4v B1 = *reinterpret_cast<const int4v*>(qrow + 36);
    int4v A2 = *reinterpret_cast<const int4v*>(qrow + 64);
    int4v B2 = *reinterpret_cast<const int4v*>(qrow + 68);
    float s0 = srow[0], s1 = srow[1], s2 = srow[2];

    stage_x(x, xs, k0, tid);
    __syncthreads();

    const short* aptr = xs + col * LDS_STRIDE + kg * 8;
    float4v acc = {0.f, 0.f, 0.f, 0.f};

    #pragma unroll 4
    for (int i = 0; i < NI; ++i) {
        int ip = (i + 3 < NI) ? (i + 3) : (NI - 1);
        int4v A3 = *reinterpret_cast<const int4v*>(qrow + ip * 32);
        int4v B3 = *reinterpret_cast<const int4v*>(qrow + ip * 32 + 4);
        float s3 = srow[ip];

        short8 bfrag = dequant8(A0, B0, s0);
        short8 afrag = *reinterpret_cast<const short8*>(aptr + i * 32);

        acc = __builtin_amdgcn_mfma_f32_16x16x32_bf16(afrag, bfrag, acc, 0, 0, 0);

        A0 = A1; B0 = B1; s0 = s1;
        A1 = A2; B1 = B2; s1 = s2;
        A2 = A3; B2 = B3; s2 = s3;
    }

    // C mapping: col = lane&15 (out row r), row = (lane>>4)*4 + i (token t)
    float* pb = pbuf + (size_t)ks * TOK * OUTF;
    #pragma unroll
    for (int i = 0; i < 4; ++i) {
        int t = kg * 4 + i;
        pb[(size_t)t * OUTF + r0 + col] = acc[i];
    }
}

__global__ __launch_bounds__(256) void reduce_bias_k(
    const float* __restrict__ pbuf, const float* __restrict__ bias,
    float* __restrict__ out)
{
    int gid = blockIdx.x * 256 + threadIdx.x;   // 32768 threads, float4 each
    int f = gid * 4;
    int t = f >> 13;       // /8192
    int r = f & (OUTF - 1);
    float4v a = *reinterpret_cast<const float4v*>(bias + r);
    #pragma unroll
    for (int s = 0; s < KSPLIT; ++s) {
        float4v p = *reinterpret_cast<const float4v*>(pbuf + (size_t)(s * TOK + t) * OUTF + r);
        a += p;
    }
    *reinterpret_cast<float4v*>(out + f) = a;
}

// Fallback when d_ws is too small: full-K per block, direct write (+bias).
__global__ __launch_bounds__(256, 4) void gemm_q8_direct(
    const float* __restrict__ x, const int* __restrict__ qw,
    const float* __restrict__ scales, const float* __restrict__ bias,
    float* __restrict__ out)
{
    __shared__ short xs[TOK * LDS_STRIDE];
    int rg = blockIdx.x;               // 0..127
    int tid = threadIdx.x;
    int wave = tid >> 6;
    int lane = tid & 63;
    int col  = lane & 15;
    int kg   = lane >> 4;
    int r0 = rg * ROWS_PER_BLOCK + wave * 16;
    int r  = r0 + col;

    float4v acc = {0.f, 0.f, 0.f, 0.f};
    for (int ks = 0; ks < KSPLIT; ++ks) {
        int k0 = ks * KR;
        __syncthreads();
        stage_x(x, xs, k0, tid);
        __syncthreads();
        const int*   qrow = qw + (size_t)r * INF + k0 + kg * 8;
        const float* srow = scales + (size_t)r * (INF / 32) + (k0 >> 5);
        const short* aptr = xs + col * LDS_STRIDE + kg * 8;

        int4v A0 = *reinterpret_cast<const int4v*>(qrow);
        int4v B0 = *reinterpret_cast<const int4v*>(qrow + 4);
        int4v A1 = *reinterpret_cast<const int4v*>(qrow + 32);
        int4v B1 = *reinterpret_cast<const int4v*>(qrow + 36);
        int4v A2 = *reinterpret_cast<const int4v*>(qrow + 64);
        int4v B2 = *reinterpret_cast<const int4v*>(qrow + 68);
        float s0 = srow[0], s1 = srow[1], s2 = srow[2];

        #pragma unroll 4
        for (int i = 0; i < NI; ++i) {
            int ip = (i + 3 < NI) ? (i + 3) : (NI - 1);
            int4v A3 = *reinterpret_cast<const int4v*>(qrow + ip * 32);
            int4v B3 = *reinterpret_cast<const int4v*>(qrow + ip * 32 + 4);
            float s3 = srow[ip];

            short8 bfrag = dequant8(A0, B0, s0);
            short8 afrag = *reinterpret_cast<const short8*>(aptr + i * 32);
            acc = __builtin_amdgcn_mfma_f32_16x16x32_bf16(afrag, bfrag, acc, 0, 0, 0);

            A0 = A1; B0 = B1; s0 = s1;
            A1 = A2; B1 = B2; s1 = s2;
            A2 = A3; B2 = B3; s2 = s3;
        }
    }
    #pragma unroll
    for (int i = 0; i < 4; ++i) {
        int t = kg * 4 + i;
        out[(size_t)t * OUTF + r0 + col] = acc[i] + bias[r0 + col];
    }
}

extern "C" void kernel_launch(void* const* d_in, const int* in_sizes, int n_in,
                              void* d_out, int out_size, void* d_ws, size_t ws_size,
                              hipStream_t stream) {
    const float* x      = (const float*)d_in[0];
    const int*   qw     = (const int*)d_in[1];
    const float* scales = (const float*)d_in[2];
    const float* bias   = (const float*)d_in[3];
    float* out = (float*)d_out;

    size_t pbytes = (size_t)KSPLIT * TOK * OUTF * sizeof(float);   // 4 MB
    if (ws_size >= pbytes) {
        float* pbuf = (float*)d_ws;
        gemm_q8_part<<<NRG * KSPLIT, 256, 0, stream>>>(x, qw, scales, pbuf);
        reduce_bias_k<<<(TOK * OUTF / 4) / 256, 256, 0, stream>>>(pbuf, bias, out);
    } else {
        gemm_q8_direct<<<NRG, 256, 0, stream>>>(x, qw, scales, bias, out);
    }
}